// Round 13
// baseline (147.922 us; speedup 1.0000x reference)
//
#include <hip/hip_runtime.h>

// Problem constants (fixed by the reference's setup_inputs)
#define NB 2          // batch
#define NN 262144     // events per batch (2^18)
#define ND 10         // temporal bins (base)
#define NR 11         // warp references (base + 1)
#define HH 256
#define WW 256
#define HWSZ 65536
#define SROWS 8       // rows per y-strip
#define NSTRIP 32     // 256 / SROWS
#define PLANE (SROWS * WW)        // 2048 pixels per strip plane
#define BINS_B (NR * NSTRIP)      // 352 bins per batch
#define NBIN (NB * BINS_B)        // 704 bins total
#define BINCAP (2u * NB * NN * NR)  // 11,534,336 worst-case entries
#define EPSF 1e-9f

// fixed-point scales for packed u64 (iwe | iwt) LDS accumulation (order-indep):
#define SC_E 2097152.0f
#define SC_T 524288.0f
#define ISC_E (1.0f / 2097152.0f)
#define ISC_T (1.0f / 524288.0f)

// R13: CONSOLIDATION on the measured-best structure (R10 = 139.9us).
// R12 lesson (counters): fused build (49us) won, but the chunk-directory scan
// regressed 37->52us -- 256 chunks x ~34 entries = 53% lane util + per-chunk
// overhead + first nonzero bank conflicts (2.77M). Global-contiguous bins are
// worth more than saving the prefix/fill split. Accounting across R1-R12 also
// shows a fixed ~42us harness poison fill inside the timed window (immovable).
// This round: R10 prep/prefix/fill/scan verbatim + the two proven R11/R12
// wins: (1) final fused into scan's last block (threadfence + ticket +
// atomic read-back), (2) prefix zeroes accum/ctr (memset shrinks to counts).
// Entry format (u64), quantization, and all arithmetic unchanged from R10.
//   bits 0-23: (wx+1)*2^15 | 24-42: (wy-ty0+1)*2^15 | 43-62: ts*2^16 | 63: pol

__device__ __forceinline__ unsigned classify(float ax, float ay, float dx, float dy, float rf)
{
    // 0xFF if no corner can land; else strip | (straddle ? 0x40 : 0)
    float wx = fmaf(rf, dx, ax);
    float wy = fmaf(rf, dy, ay);
    int xi = (int)floorf(wx);
    int yi = (int)floorf(wy);
    if (xi + 1 < 0 || xi >= WW || yi + 1 < 0 || yi >= HH) return 0xFFu;
    int rr = yi < 0 ? 0 : yi;
    unsigned s = (unsigned)(rr >> 3);                 // SROWS = 8
    unsigned str = (yi >= 0 && yi + 1 < HH && ((yi & 7) == 7)) ? 0x40u : 0u;
    return s | str;
}

__global__ __launch_bounds__(1024) void cm_prep(
    const float* __restrict__ events,
    const float* __restrict__ flow,
    float4* __restrict__ rec,
    float* __restrict__ tspol,
    unsigned* __restrict__ counts)
{
    __shared__ unsigned hist[BINS_B];           // 352 counters, 1.4 KB
    for (int i = threadIdx.x; i < BINS_B; i += 1024) hist[i] = 0u;
    __syncthreads();

    int gid = blockIdx.x * 1024 + threadIdx.x;  // grid covers NB*NN exactly
    int b = gid >> 18;                          // uniform per block

    const float* e = events + (size_t)gid * 5;
    float x  = e[0];
    float y  = e[1];
    float t  = e[2];
    float ts = e[3];
    float p  = e[4];

    int zi = (int)floorf(t);
    zi = zi < 0 ? 0 : (zi > ND - 1 ? ND - 1 : zi);
    int x0 = (int)floorf(x);
    x0 = x0 < 0 ? 0 : (x0 > WW - 2 ? WW - 2 : x0);
    int y0 = (int)floorf(y);
    y0 = y0 < 0 ? 0 : (y0 > HH - 2 ? HH - 2 : y0);
    float fx = fminf(fmaxf(x - (float)x0, 0.0f), 1.0f);
    float fy = fminf(fmaxf(y - (float)y0, 0.0f), 1.0f);

    const float2* f2 = (const float2*)flow + ((size_t)b * ND + zi) * HWSZ;
    float2 f00 = f2[y0 * WW + x0];
    float2 f01 = f2[y0 * WW + x0 + 1];
    float2 f10 = f2[(y0 + 1) * WW + x0];
    float2 f11 = f2[(y0 + 1) * WW + x0 + 1];
    float w00 = (1.0f - fx) * (1.0f - fy);
    float w01 = fx * (1.0f - fy);
    float w10 = (1.0f - fx) * fy;
    float w11 = fx * fy;
    float dx = w00 * f00.x + w01 * f01.x + w10 * f10.x + w11 * f11.x;
    float dy = w00 * f00.y + w01 * f01.y + w10 * f10.y + w11 * f11.y;
    float ax = fmaf(-t, dx, x);
    float ay = fmaf(-t, dy, y);

    rec[gid] = make_float4(ax, ay, dx, dy);
    int pi = (p != 0.0f) ? 1 : 0;
    tspol[gid] = __int_as_float(__float_as_int(ts) | (pi << 31));   // ts >= 0

    #pragma unroll
    for (int r = 0; r < NR; ++r) {
        unsigned c = classify(ax, ay, dx, dy, (float)r);
        if (c != 0xFFu) {
            int bin = r * NSTRIP + (int)(c & 31u);
            atomicAdd(&hist[bin], 1u);
            if (c & 0x40u) atomicAdd(&hist[bin + 1], 1u);   // straddle dup
        }
    }
    __syncthreads();
    for (int i = threadIdx.x; i < BINS_B; i += 1024) {
        unsigned c = hist[i];
        if (c) atomicAdd(&counts[b * BINS_B + i], c);
    }
}

// exclusive prefix over all 704 bins; also zeroes accum + arrival counter
// (replaces the old accum memset and enables the fused final in cm_scan)
__global__ __launch_bounds__(1024) void cm_prefix(
    const unsigned* __restrict__ counts,
    unsigned* __restrict__ starts,
    unsigned* __restrict__ cursors,
    float* __restrict__ accum,
    unsigned* __restrict__ ctr)
{
    __shared__ unsigned sa[1024];
    int tid = threadIdx.x;

    unsigned v = (tid < NBIN) ? counts[tid] : 0u;
    sa[tid] = v;
    __syncthreads();
    for (int off = 1; off < 1024; off <<= 1) {
        unsigned x = sa[tid];
        if (tid >= off) x += sa[tid - off];
        __syncthreads();
        sa[tid] = x;
        __syncthreads();
    }
    if (tid < NBIN) {
        unsigned ex = tid ? sa[tid - 1] : 0u;
        starts[tid] = ex;
        cursors[tid] = ex;
    }
    if (tid == 0) starts[NBIN] = sa[NBIN - 1];
    if (tid >= 1024 - 64 && tid < 1024 - 64 + 64) accum[tid - (1024 - 64)] = 0.0f;
    if (tid == 512) *ctr = 0u;
}

__global__ __launch_bounds__(1024) void cm_fill(
    const float4* __restrict__ rec,
    const float* __restrict__ tspol,
    unsigned long long* __restrict__ bins,
    unsigned* __restrict__ cursors)
{
    __shared__ unsigned char stash[2048 * NR];    // 22.5 KB (2 events/thread x 11 r)
    __shared__ unsigned cnt[BINS_B];              // 1.4 KB
    __shared__ unsigned base[BINS_B];             // 1.4 KB

    for (int i = threadIdx.x; i < BINS_B; i += 1024) cnt[i] = 0u;
    __syncthreads();

    int e0 = blockIdx.x * 2048;                   // 256 blocks cover NB*NN
    int b = e0 >> 18;                             // uniform per block

    float4 ea[2];
    float tp[2];
    #pragma unroll
    for (int k = 0; k < 2; ++k) {
        int el = e0 + k * 1024 + threadIdx.x;
        ea[k] = rec[el];
        tp[k] = tspol[el];
    }

    #pragma unroll
    for (int k = 0; k < 2; ++k) {
        int sl = (k * 1024 + threadIdx.x) * NR;
        for (int r = 0; r < NR; ++r) {
            unsigned c = classify(ea[k].x, ea[k].y, ea[k].z, ea[k].w, (float)r);
            stash[sl + r] = (unsigned char)c;
            if (c != 0xFFu) {
                int bin = r * NSTRIP + (int)(c & 31u);
                atomicAdd(&cnt[bin], 1u);
                if (c & 0x40u) atomicAdd(&cnt[bin + 1], 1u);
            }
        }
    }
    __syncthreads();
    for (int i = threadIdx.x; i < BINS_B; i += 1024) {
        unsigned c = cnt[i];
        base[i] = c ? atomicAdd(&cursors[b * BINS_B + i], c) : 0u;
    }
    __syncthreads();
    for (int i = threadIdx.x; i < BINS_B; i += 1024) cnt[i] = 0u;  // reuse as ranks
    __syncthreads();

    #pragma unroll
    for (int k = 0; k < 2; ++k) {
        int sl = (k * 1024 + threadIdx.x) * NR;
        float tpv = tp[k];
        unsigned pol = (unsigned)__float_as_int(tpv) >> 31;
        float tsv = fabsf(tpv);
        unsigned et = __float2uint_rn(tsv * 65536.0f);            // 20 bits
        unsigned long long hdr = ((unsigned long long)et << 43) |
                                 ((unsigned long long)pol << 63);
        for (int r = 0; r < NR; ++r) {
            unsigned c = stash[sl + r];
            if (c != 0xFFu) {
                float rf = (float)r;
                float wx = fmaf(rf, ea[k].z, ea[k].x);   // bit-identical chain
                float wy = fmaf(rf, ea[k].w, ea[k].y);
                int sid = (int)(c & 31u);
                float ty0f = (float)(sid * SROWS);
                unsigned ex = __float2uint_rn((wx + 1.0f) * 32768.0f);        // 24b
                unsigned ey = __float2uint_rn((wy - ty0f + 1.0f) * 32768.0f); // 19b
                unsigned long long ent = hdr | (unsigned long long)ex |
                                         ((unsigned long long)ey << 24);
                int bin = r * NSTRIP + sid;
                unsigned rank = atomicAdd(&cnt[bin], 1u);
                bins[base[bin] + rank] = ent;
                if (c & 0x40u) {                          // straddle dup into s+1
                    unsigned ey2 = __float2uint_rn((wy - ty0f - (float)SROWS + 1.0f) * 32768.0f);
                    unsigned long long ent2 = hdr | (unsigned long long)ex |
                                              ((unsigned long long)ey2 << 24);
                    unsigned rank2 = atomicAdd(&cnt[bin + 1], 1u);
                    bins[base[bin + 1] + rank2] = ent2;
                }
            }
        }
    }
}

__global__ __launch_bounds__(1024) void cm_scan(
    const unsigned long long* __restrict__ bins,
    const unsigned* __restrict__ starts,
    float* __restrict__ accum,
    unsigned* __restrict__ ctr,
    float* __restrict__ out)
{
    __shared__ unsigned long long acc8[2 * PLANE];   // 32 KB: [pol][px] packed (iwe|iwt)
    __shared__ float red[32];                        // wave partials / last flag

    int blk = blockIdx.x;                            // 0 .. NBIN-1
    int b  = blk / BINS_B;
    int rm = blk - b * BINS_B;
    int r  = rm >> 5;

    for (int i = threadIdx.x; i < 2 * PLANE; i += 1024) acc8[i] = 0ull;
    __syncthreads();

    unsigned lo = starts[blk];
    unsigned hi = starts[blk + 1];

    auto process = [&](unsigned long long e) {
        float wx  = (float)(unsigned)(e & 0xFFFFFFu) * (1.0f / 32768.0f) - 1.0f;
        float wyr = (float)(unsigned)((e >> 24) & 0x7FFFFu) * (1.0f / 32768.0f) - 1.0f;
        float tsv = (float)(unsigned)((e >> 43) & 0xFFFFFu) * (1.0f / 65536.0f);
        int pi = (int)(e >> 63);
        float fwx = floorf(wx);
        float fwy = floorf(wyr);
        int xi = (int)fwx;
        int yi = (int)fwy;                           // strip-relative: -1..8
        float axf = wx - fwx;
        float ayf = wyr - fwy;
        unsigned long long* ap = acc8 + pi * PLANE;
        float c00 = (1.0f - axf) * (1.0f - ayf);
        float c01 = axf * (1.0f - ayf);
        float c10 = (1.0f - axf) * ayf;
        float c11 = axf * ayf;
        #define CM_CORNER(XI, YI, WV)                                          \
            if ((XI) >= 0 && (XI) < WW && (YI) >= 0 && (YI) < SROWS) {         \
                int liq = (YI) * WW + (XI);                                    \
                unsigned pe = __float2uint_rn((WV) * SC_E);                    \
                unsigned pt = __float2uint_rn((WV) * tsv * SC_T);              \
                atomicAdd(&ap[liq],                                            \
                          ((unsigned long long)pt << 32) | (unsigned long long)pe); \
            }
        CM_CORNER(xi,     yi,     c00)
        CM_CORNER(xi + 1, yi,     c01)
        CM_CORNER(xi,     yi + 1, c10)
        CM_CORNER(xi + 1, yi + 1, c11)
        #undef CM_CORNER
    };

    // head-align to even entry index so uint4 loads are 16B-aligned
    unsigned lo2 = lo + (lo & 1u);
    if ((lo & 1u) && threadIdx.x == 0 && lo < hi) process(bins[lo]);

    const uint4* bv = (const uint4*)bins;
    for (unsigned bse = lo2 + 4u * threadIdx.x; bse < hi; bse += 4096u) {
        uint4 A = bv[bse >> 1];                 // entries bse, bse+1
        uint4 B = bv[(bse >> 1) + 1];           // entries bse+2, bse+3 (alloc slack ok)
        __builtin_amdgcn_sched_barrier(0);      // pin both wide loads ahead of use
        unsigned long long e0 = (unsigned long long)A.x | ((unsigned long long)A.y << 32);
        unsigned long long e1 = (unsigned long long)A.z | ((unsigned long long)A.w << 32);
        unsigned long long e2 = (unsigned long long)B.x | ((unsigned long long)B.y << 32);
        unsigned long long e3 = (unsigned long long)B.z | ((unsigned long long)B.w << 32);
        process(e0);
        if (bse + 1 < hi) process(e1);
        if (bse + 2 < hi) process(e2);
        if (bse + 3 < hi) process(e3);
    }
    __syncthreads();

    float ss = 0.0f, ins = 0.0f;
    for (int i = threadIdx.x; i < PLANE; i += 1024) {   // 2 iters (PLANE=2048)
        unsigned long long v0 = acc8[i];
        unsigned long long v1 = acc8[PLANE + i];
        unsigned e0i = (unsigned)(v0 & 0xFFFFFFFFull);
        unsigned e1i = (unsigned)(v1 & 0xFFFFFFFFull);
        float e0 = (float)e0i * ISC_E;
        float t0 = (float)(unsigned)(v0 >> 32) * ISC_T;
        float e1 = (float)e1i * ISC_E;
        float t1 = (float)(unsigned)(v1 >> 32) * ISC_T;
        float a0 = t0 / (e0 + EPSF);
        float a1 = t1 / (e1 + EPSF);
        ss += a0 * a0 + a1 * a1;
        ins += ((e0i | e1i) != 0u) ? 1.0f : 0.0f;
    }
    #pragma unroll
    for (int off = 32; off > 0; off >>= 1) {
        ss  += __shfl_down(ss, off, 64);
        ins += __shfl_down(ins, off, 64);
    }
    int lane = threadIdx.x & 63;
    int wv = threadIdx.x >> 6;                      // 0..15
    if (lane == 0) { red[2 * wv] = ss; red[2 * wv + 1] = ins; }
    __syncthreads();
    if (threadIdx.x == 0) {
        float tss = 0.0f, tin = 0.0f;
        #pragma unroll
        for (int w = 0; w < 16; ++w) { tss += red[2 * w]; tin += red[2 * w + 1]; }
        int br = b * NR + r;
        atomicAdd(&accum[br * 2],     tss);
        atomicAdd(&accum[br * 2 + 1], tin);
        __threadfence();
        unsigned old = atomicAdd(ctr, 1u);
        red[0] = (old == NBIN - 1) ? 1.0f : 0.0f;   // am I the last block?
    }
    __syncthreads();
    if (red[0] != 0.0f && threadIdx.x < NB * NR) {
        // fused final: atomic read-back dodges stale L1 after cross-CU adds
        float num = atomicAdd(&accum[threadIdx.x * 2],     0.0f);
        float den = atomicAdd(&accum[threadIdx.x * 2 + 1], 0.0f);
        out[threadIdx.x] = num / (den + EPSF);
    }
}

extern "C" void kernel_launch(void* const* d_in, const int* in_sizes, int n_in,
                              void* d_out, int out_size, void* d_ws, size_t ws_size,
                              hipStream_t stream) {
    const float* events = (const float*)d_in[0];
    const float* flow   = (const float*)d_in[1];

    char* ws = (char*)d_ws;
    size_t off = 0;
    unsigned long long* bins = (unsigned long long*)(ws + off);
    off += (size_t)BINCAP * 8;                                                // 92,274,688
    float4* rec = (float4*)(ws + off);         off += (size_t)NB * NN * sizeof(float4); // 8,388,608
    float* tspol = (float*)(ws + off);         off += (size_t)NB * NN * sizeof(float);  // 2,097,152
    unsigned* counts = (unsigned*)(ws + off);  off += NBIN * 4;                          // 2,816
    unsigned* starts = (unsigned*)(ws + off);  off += (NBIN + 1) * 4 + 60; off &= ~63ull;
    unsigned* cursors = (unsigned*)(ws + off); off += NBIN * 4 + 60; off &= ~63ull;
    float* accum = (float*)(ws + off);         off += 64 * 4;
    unsigned* ctr = (unsigned*)(ws + off);     off += 64;
    // total ~103 MB of the 256 MiB workspace; 4 dispatches + one 3 KB memset

    hipMemsetAsync(counts, 0, NBIN * 4, stream);   // counts only (accum/ctr zeroed in prefix)

    cm_prep<<<NB * NN / 1024, 1024, 0, stream>>>(events, flow, rec, tspol, counts);

    cm_prefix<<<1, 1024, 0, stream>>>(counts, starts, cursors, accum, ctr);

    cm_fill<<<NB * NN / 2048, 1024, 0, stream>>>(rec, tspol, bins, cursors);

    cm_scan<<<NBIN, 1024, 0, stream>>>(bins, starts, accum, ctr, (float*)d_out);
}